// Round 3
// baseline (1582.050 us; speedup 1.0000x reference)
//
#include <hip/hip_runtime.h>
#include <stdint.h>

typedef __attribute__((ext_vector_type(8))) _Float16 h8v;
typedef __attribute__((ext_vector_type(2))) _Float16 h2v;
typedef __attribute__((ext_vector_type(4))) float f4v;

#define NLVL 6
#define TSZ (1u << 19)

__device__ __forceinline__ float b2f(unsigned short u){
  union { unsigned int i; float f; } v; v.i = ((unsigned)u) << 16; return v.f;
}
__device__ __forceinline__ unsigned short f2b(float f){
  unsigned x = __float_as_uint(f);
  x = (x + 0x7fffu + ((x >> 16) & 1u)) >> 16;
  return (unsigned short)x;
}
__device__ __forceinline__ unsigned short f2h(float f){
  union { _Float16 h; unsigned short u; } v; v.h = (_Float16)f; return v.u;
}
__device__ __forceinline__ float ldx(const void* p, long i, int isb){
  return isb ? b2f(((const unsigned short*)p)[i]) : ((const float*)p)[i];
}

// Abuf swizzle: element (row, k) -> row*256 + ((k/8 ^ (row&7))*8) + k%8
#define SWZ(row,k) ((row)*256 + ((((k) >> 3) ^ ((row) & 7)) << 3) + ((k) & 7))

// ---------------- dtype sniffing ----------------
__global__ void kdetect(const unsigned short* inpos, int* flag){
  __shared__ int cnt;
  if (threadIdx.x == 0) cnt = 0;
  __syncthreads();
  float f = b2f(inpos[threadIdx.x * 2]);
  int ok = (f == f) && (fabsf(f) <= 1.0f);
  atomicAdd(&cnt, ok);
  __syncthreads();
  if (threadIdx.x == 0) *flag = (cnt >= 120);
}

// ---------------- ws layout ----------------
// [0,16):            int flag
// [16, +L*N*2*4):    grid features g[level][point][2] (f32)
// [wt_off, +12*65536*2): weights in FRAGMENT layout, fp16:
//     wt2[wi][wv(4)][kc(8)][ct(4)][lane(64)][8]   (n = wv*64+ct*16+sx, k = kc*32+q*8+j, lane=q*16+sx)
// [c_off, +7168*4):  f32 consts: W0s[768] | sb0[256] | sbs[1536] | sbh[1536] | A2pi[3072]

__global__ void kconsts(const void* ffnA, const void* W0, const void* b0,
                        const void* bs, const void* bh, char* ws, int Npts){
  const int flag = *(const int*)ws;
  const size_t wt_off = 16 + (size_t)NLVL * Npts * 8;
  float* cst = (float*)(ws + wt_off + (size_t)12 * 65536 * 2);
  int idx = blockIdx.x * 256 + threadIdx.x;
  float v;
  if (idx < 768)        v = 5.0f  * ldx(W0, idx, flag);
  else if (idx < 1024)  v = 5.0f  * ldx(b0, idx - 768, flag);
  else if (idx < 2560)  v = 5.0f  * ldx(bs, idx - 1024, flag);
  else if (idx < 4096)  v = 10.0f * ldx(bh, idx - 2560, flag);
  else { int j = idx - 4096; int l = j >> 9;
         v = 31.415926535897932f * (float)(1 << l) * ldx(ffnA, j, flag); }
  cst[idx] = v;
}

// ---------------- weight repack into fragment order (dst-coalesced) ----------------
__global__ void kwt(const void* Wsv, const void* Whv, char* ws, int Npts){
  const int flag = *(const int*)ws;
  unsigned short* wt = (unsigned short*)(ws + 16 + (size_t)NLVL * Npts * 8);
  int e = blockIdx.x * 256 + threadIdx.x;          // 786432 total, e == dst index
  int j  = e & 7;
  int lane = (e >> 3) & 63;
  int ct = (e >> 9) & 3;
  int kc = (e >> 11) & 7;
  int wv = (e >> 14) & 3;
  int wi = e >> 16;
  int sx = lane & 15, q = lane >> 4;
  int n = wv * 64 + ct * 16 + sx;
  int k = kc * 32 + q * 8 + j;
  const void* src = (wi < 6) ? Wsv : Whv;
  int m = (wi < 6) ? wi : wi - 6;
  long si = (long)m * 65536 + k * 256 + n;         // W[k][n] row-major
  float w = flag ? b2f(((const unsigned short*)src)[si]) : ((const float*)src)[si];
  wt[e] = f2h(w);
}

// ---------------- hash grid features ----------------
__global__ void kgrid(const void* inpos, const void* tbl, char* ws, int Npts){
  const int flag = *(const int*)ws;
  float* gf = (float*)(ws + 16);
  int n = blockIdx.x * 256 + threadIdx.x;
  int l = blockIdx.y;
  long b3 = (long)n * 3;
  float x = ldx(inpos, b3 + 0, flag), y = ldx(inpos, b3 + 1, flag), z = ldx(inpos, b3 + 2, flag);
  float res = (float)(16 << l);
  float px = ((x + 1.0f) * 0.5f) * res;
  float py = ((y + 1.0f) * 0.5f) * res;
  float pz = ((z + 1.0f) * 0.5f) * res;
  float fx = floorf(px), fy = floorf(py), fz = floorf(pz);
  float rx = px - fx, ry = py - fy, rz = pz - fz;
  unsigned cx = (unsigned)(int)fx, cy = (unsigned)(int)fy, cz = (unsigned)(int)fz;
  unsigned ax0 = cx,                 ax1 = cx + 1u;
  unsigned ay0 = cy * 2654435761u,   ay1 = (cy + 1u) * 2654435761u;
  unsigned az0 = cz * 805459861u,    az1 = (cz + 1u) * 805459861u;
  float g0 = 0.f, g1 = 0.f;
  #pragma unroll
  for (int c = 0; c < 8; c++){
    unsigned h = (((c & 4) ? ax1 : ax0) ^ ((c & 2) ? ay1 : ay0) ^ ((c & 1) ? az1 : az0)) & (TSZ - 1u);
    float w = ((c & 4) ? rx : 1.0f - rx) * ((c & 2) ? ry : 1.0f - ry) * ((c & 1) ? rz : 1.0f - rz);
    long e = ((long)l * TSZ + h) * 2;
    float f0, f1;
    if (flag){
      unsigned v = *(const unsigned*)((const unsigned short*)tbl + e);
      f0 = b2f((unsigned short)(v & 0xffffu)); f1 = b2f((unsigned short)(v >> 16));
    } else {
      const float* tp = (const float*)tbl + e; f0 = tp[0]; f1 = tp[1];
    }
    g0 += w * f0; g1 += w * f1;
  }
  float2 o; o.x = g0; o.y = g1;
  *(float2*)(gf + ((long)l * Npts + n) * 2) = o;
}

// ---------------- fused MLP ----------------
// 256 threads = 4 waves; block tile 64 rows x 256 cols; wave tile 64x64.
// A in LDS (swizzled, conflict-free); B streamed from global in fragment
// layout (L2-broadcast), software-pipelined 1 kc ahead; 2 barriers per even
// layer only. xo accumulated as packed fp16 to stay <=170 VGPR (3 waves/SIMD).
__global__ __launch_bounds__(256, 3) void kmain(const void* inpos, char* ws, void* outp, int Npts){
  __shared__ __align__(16) unsigned short Abuf[64 * 256];
  __shared__ __align__(16) float g_p[NLVL * 64 * 2];

  const int tid = threadIdx.x;
  const int flag = *(const int*)ws;
  const size_t wt_off = 16 + (size_t)NLVL * Npts * 8;
  const unsigned short* wt2 = (const unsigned short*)(ws + wt_off);
  const float* cst = (const float*)(ws + wt_off + (size_t)12 * 65536 * 2);
  const float* gf = (const float*)(ws + 16);
  const int r0 = blockIdx.x * 64;

  // stage grid features for this row tile: g_p[l][row][2]
  for (int idx = tid; idx < NLVL * 64; idx += 256){
    int l = idx >> 6, row = idx & 63;
    *(float2*)(g_p + l * 128 + row * 2) =
        *(const float2*)(gf + ((size_t)l * Npts + r0 + row) * 2);
  }
  { // layer 0: x = sin(5*(pos@W0 + b0)) -> Abuf (fp16, swizzled)
    int lr = tid >> 2, c0 = (tid & 3) * 64;
    long bb = (long)(r0 + lr) * 3;
    float p0v = ldx(inpos, bb + 0, flag), p1v = ldx(inpos, bb + 1, flag), p2v = ldx(inpos, bb + 2, flag);
    #pragma unroll
    for (int b8 = 0; b8 < 8; b8++){
      h8v v;
      #pragma unroll
      for (int j = 0; j < 8; j++){
        int d = c0 + b8 * 8 + j;
        v[j] = (_Float16)__sinf(p0v * cst[d] + p1v * cst[256 + d] + p2v * cst[512 + d] + cst[768 + d]);
      }
      *(h8v*)(Abuf + lr * 256 + ((((c0 >> 3) + b8) ^ (lr & 7)) << 3)) = v;
    }
  }
  __syncthreads();

  const int lane = tid & 63, wv = tid >> 6;
  const int q = lane >> 4, sx = lane & 15;
  const int sx7 = sx & 7;
  const int wcol = wv * 64;
  int arow[4];
  #pragma unroll
  for (int rt = 0; rt < 4; rt++) arow[rt] = (rt * 16 + sx) * 256;
  const unsigned short* bbase = wt2 + wv * 16384 + lane * 8;

  h2v xo[4][4][2];
  #pragma unroll
  for (int a = 0; a < 4; a++)
    #pragma unroll
    for (int b = 0; b < 4; b++){
      h2v z; z[0] = (_Float16)0.f; z[1] = (_Float16)0.f;
      xo[a][b][0] = z; xo[a][b][1] = z;
    }

  h8v bn[4];
  #pragma unroll
  for (int ct = 0; ct < 4; ct++) bn[ct] = *(const h8v*)(bbase + ct * 512);  // s=0, kc=0

  const f4v zf = {0.f, 0.f, 0.f, 0.f};
  #pragma unroll 1
  for (int s = 0; s < 12; s++){
    const int li = s >> 1;
    const int wi = (s & 1) ? (6 + li) : li;
    f4v acc[4][4];
    #pragma unroll
    for (int a = 0; a < 4; a++)
      #pragma unroll
      for (int b = 0; b < 4; b++) acc[a][b] = zf;
    #pragma unroll 1
    for (int kc = 0; kc < 8; kc++){
      h8v bfr[4];
      #pragma unroll
      for (int ct = 0; ct < 4; ct++) bfr[ct] = bn[ct];
      if (!(s == 11 && kc == 7)){
        int nwi, nkc;
        if (kc < 7){ nwi = wi; nkc = kc + 1; }
        else { int s2 = s + 1; nwi = (s2 & 1) ? (6 + (s2 >> 1)) : (s2 >> 1); nkc = 0; }
        const unsigned short* bp = bbase + nwi * 65536 + nkc * 2048;
        #pragma unroll
        for (int ct = 0; ct < 4; ct++) bn[ct] = *(const h8v*)(bp + ct * 512);
      }
      h8v afr[4];
      #pragma unroll
      for (int rt = 0; rt < 4; rt++)
        afr[rt] = *(const h8v*)(Abuf + arow[rt] + ((((kc << 2) + q) ^ sx7) << 3));
      #pragma unroll
      for (int rt = 0; rt < 4; rt++)
        #pragma unroll
        for (int ct = 0; ct < 4; ct++)
          acc[rt][ct] = __builtin_amdgcn_mfma_f32_16x16x32_f16(afr[rt], bfr[ct], acc[rt][ct], 0, 0, 0);
    }
    if ((s & 1) == 0){
      __syncthreads();   // all waves done reading Abuf for this layer
      #pragma unroll
      for (int ct = 0; ct < 4; ct++){
        int col = wcol + ct * 16 + sx;
        float sb = cst[1024 + li * 256 + col];
        float a0 = cst[4096 + li * 512 + col];
        float a1 = cst[4096 + li * 512 + 256 + col];
        #pragma unroll
        for (int rt = 0; rt < 4; rt++)
          #pragma unroll
          for (int r = 0; r < 4; r++){
            int row = rt * 16 + q * 4 + r;
            float gg0 = g_p[li * 128 + row * 2], gg1 = g_p[li * 128 + row * 2 + 1];
            float v = __sinf(5.0f * acc[rt][ct][r] + sb) + __sinf(a0 * gg0 + a1 * gg1);
            Abuf[SWZ(row, col)] = f2h(v);
          }
      }
      __syncthreads();
    } else {
      #pragma unroll
      for (int ct = 0; ct < 4; ct++){
        int col = wcol + ct * 16 + sx;
        float sb = cst[2560 + li * 256 + col];
        #pragma unroll
        for (int rt = 0; rt < 4; rt++)
          #pragma unroll
          for (int rp = 0; rp < 2; rp++){
            float v0 = __sinf(10.0f * acc[rt][ct][rp * 2 + 0] + sb);
            float v1 = __sinf(10.0f * acc[rt][ct][rp * 2 + 1] + sb);
            h2v t; t[0] = (_Float16)v0; t[1] = (_Float16)v1;
            xo[rt][ct][rp] = xo[rt][ct][rp] + t;
          }
      }
    }
  }
  if (flag){
    unsigned short* ob = (unsigned short*)outp;
    #pragma unroll
    for (int rt = 0; rt < 4; rt++)
      #pragma unroll
      for (int ct = 0; ct < 4; ct++)
        #pragma unroll
        for (int r = 0; r < 4; r++){
          long row = (long)r0 + rt * 16 + q * 4 + r;
          ob[row * 256 + (wcol + ct * 16 + sx)] = f2b((float)xo[rt][ct][r >> 1][r & 1]);
        }
  } else {
    float* of = (float*)outp;
    #pragma unroll
    for (int rt = 0; rt < 4; rt++)
      #pragma unroll
      for (int ct = 0; ct < 4; ct++)
        #pragma unroll
        for (int r = 0; r < 4; r++){
          long row = (long)r0 + rt * 16 + q * 4 + r;
          of[row * 256 + (wcol + ct * 16 + sx)] = (float)xo[rt][ct][r >> 1][r & 1];
        }
  }
}

extern "C" void kernel_launch(void* const* d_in, const int* in_sizes, int n_in,
                              void* d_out, int out_size, void* d_ws, size_t ws_size,
                              hipStream_t stream){
  (void)n_in; (void)out_size; (void)ws_size;
  const void* inpos = d_in[0];
  const void* tbl   = d_in[1];
  const void* ffnA  = d_in[2];
  const void* W0    = d_in[3];
  const void* b0    = d_in[4];
  const void* Wsv   = d_in[5];
  const void* bsv   = d_in[6];
  const void* Whv   = d_in[7];
  const void* bhv   = d_in[8];
  int Npts = in_sizes[0] / 3;              // 262144
  char* ws = (char*)d_ws;
  kdetect<<<1, 128, 0, stream>>>((const unsigned short*)inpos, (int*)d_ws);
  kconsts<<<28, 256, 0, stream>>>(ffnA, W0, b0, bsv, bhv, ws, Npts);
  kwt<<<3072, 256, 0, stream>>>(Wsv, Whv, ws, Npts);
  kgrid<<<dim3(Npts / 256, NLVL), 256, 0, stream>>>(inpos, tbl, ws, Npts);
  kmain<<<Npts / 64, 256, 0, stream>>>(inpos, ws, d_out, Npts);
}